// Round 3
// baseline (139.522 us; speedup 1.0000x reference)
//
#include <hip/hip_runtime.h>
#include <math.h>

#define DIM 128
#define NUM_NEG 20
#define BATCH 16384
#define INV_T (1.0f / 0.07f)
#define NROWS 21  // 1 positive (context) + 20 negatives

// One 64-lane wave per batch element, split as 4 groups x 16 lanes.
// Key change vs R1: ALL memory is prefetched with maximum MLP.
//  - 6 per-lane row indices loaded up front (2 cache lines, independent)
//  - all 12 row gathers (2 x float4 per row-group slot) + 2 target loads
//    issued back-to-back into registers BEFORE any consume
//  - invalid slots (r=21..23) alias row 20's node -> same cache lines,
//    zero extra traffic, masked to -inf afterwards (branchless loads)
__global__ __launch_bounds__(256) void infonce_kernel(
    const float* __restrict__ emb,
    const int* __restrict__ targets,
    const int* __restrict__ contexts,
    const int* __restrict__ negatives,
    float* __restrict__ out)
{
    __shared__ float block_part[4];
    const int lane = threadIdx.x & 63;
    const int wib  = threadIdx.x >> 6;   // wave in block
    const int b    = blockIdx.x * 4 + wib;
    const int sub  = lane & 15;          // 8-float chunk within the row
    const int grp  = lane >> 4;          // row-group 0..3

    // ---- phase 1: all index loads, issued together ----
    const int* __restrict__ negb = negatives + b * NUM_NEG;
    int node[6];
    #pragma unroll
    for (int it = 0; it < 6; ++it) {
        const int r = it * 4 + grp;      // row id 0..23 (21..23 invalid)
        const int k = (r == 0) ? 0 : ((r <= NUM_NEG) ? (r - 1) : (NUM_NEG - 1));
        node[it] = (r == 0) ? contexts[b] : negb[k];
    }
    const int t_idx = targets[b];

    // ---- phase 2: all row gathers, issued back-to-back ----
    const float4* tp =
        reinterpret_cast<const float4*>(emb + (size_t)t_idx * DIM + sub * 8);
    const float4 t0 = tp[0];
    const float4 t1 = tp[1];

    float4 r0[6], r1[6];
    #pragma unroll
    for (int it = 0; it < 6; ++it) {
        const float4* vp = reinterpret_cast<const float4*>(
            emb + (size_t)node[it] * DIM + sub * 8);
        r0[it] = vp[0];
        r1[it] = vp[1];
    }

    // ---- phase 3: dot + 16-lane reduce per slot (independent chains) ----
    float score[6];
    #pragma unroll
    for (int it = 0; it < 6; ++it) {
        float p = t0.x * r0[it].x + t0.y * r0[it].y
                + t0.z * r0[it].z + t0.w * r0[it].w
                + t1.x * r1[it].x + t1.y * r1[it].y
                + t1.z * r1[it].z + t1.w * r1[it].w;
        p += __shfl_xor(p, 1);
        p += __shfl_xor(p, 2);
        p += __shfl_xor(p, 4);
        p += __shfl_xor(p, 8);
        const int r = it * 4 + grp;
        score[it] = (r < NROWS) ? p * INV_T : -INFINITY;
    }

    // ---- phase 4: logsumexp (local 6, then merge across 4 groups) ----
    float m = score[0];
    #pragma unroll
    for (int i = 1; i < 6; ++i) m = fmaxf(m, score[i]);
    float s = 0.0f;
    #pragma unroll
    for (int i = 0; i < 6; ++i) s += expf(score[i] - m);

    #pragma unroll
    for (int mask = 16; mask <= 32; mask <<= 1) {
        const float mo = __shfl_xor(m, mask);
        const float so = __shfl_xor(s, mask);
        const float mn = fmaxf(m, mo);
        s = s * expf(m - mn) + so * expf(mo - mn);
        m = mn;
    }

    // positive score: row 0 = group 0, slot 0 -> lane 0
    const float pos = __shfl(score[0], 0);
    const float loss = (m + logf(s) - pos) * (1.0f / BATCH);

    if (lane == 0) block_part[wib] = loss;
    __syncthreads();
    if (threadIdx.x == 0) {
        atomicAdd(out, block_part[0] + block_part[1] +
                       block_part[2] + block_part[3]);
    }
}

extern "C" void kernel_launch(void* const* d_in, const int* in_sizes, int n_in,
                              void* d_out, int out_size, void* d_ws, size_t ws_size,
                              hipStream_t stream) {
    const float* emb       = (const float*)d_in[0];
    const int*   targets   = (const int*)d_in[1];
    const int*   contexts  = (const int*)d_in[2];
    const int*   negatives = (const int*)d_in[3];
    float* out = (float*)d_out;

    // d_out is re-poisoned to 0xAA before every launch — zero it on-stream.
    hipMemsetAsync(out, 0, sizeof(float), stream);

    infonce_kernel<<<dim3(BATCH / 4), dim3(256), 0, stream>>>(
        emb, targets, contexts, negatives, out);
}